// Round 1
// baseline (609.071 us; speedup 1.0000x reference)
//
#include <hip/hip_runtime.h>
#include <cstdint>
#include <cstddef>

// ---------------- problem constants ----------------
#define DMODEL 1024
#define DINNER 2048
#define DSTATE 16
#define DCONV  4
#define DTRANK 64
#define BSZ    2
#define SEQL   2048
#define MROWS  (BSZ*SEQL)          // 4096
#define NCHUNK 32                  // scan chunks per sequence
#define CLEN   (SEQL/NCHUNK)       // 64

typedef __bf16 bf16;
typedef bf16  bf16x8 __attribute__((ext_vector_type(8)));
typedef bf16  bf16x4 __attribute__((ext_vector_type(4)));
typedef float floatx4 __attribute__((ext_vector_type(4)));

__device__ __forceinline__ float fsigmoid(float x){ return 1.f/(1.f+__expf(-x)); }
__device__ __forceinline__ float fsilu(float x){ return x*fsigmoid(x); }

__device__ __forceinline__ void gload_lds16(const void* g, void* l){
  __builtin_amdgcn_global_load_lds((__attribute__((address_space(1))) void*)g,
                                   (__attribute__((address_space(3))) void*)l,
                                   16, 0, 0);
}

// ---------------- elementwise cast fp32 -> bf16 (vec4) ----------------
__global__ void k_cast_bf16(const float* __restrict__ in, bf16* __restrict__ out, int n){
  int i = (blockIdx.x*blockDim.x + threadIdx.x)*4;
  if (i < n){
    float4 v = *(const float4*)(in + i);
    bf16x4 o; o[0]=(bf16)v.x; o[1]=(bf16)v.y; o[2]=(bf16)v.z; o[3]=(bf16)v.w;
    *(bf16x4*)(out + i) = o;
  }
}

// ---------------- transpose + cast: out[c][r] = in[r][c], zero-pad rows >= C ----------------
__global__ void k_transpose_cast(const float* __restrict__ in, bf16* __restrict__ out,
                                 int R, int C, int outR){
  __shared__ float tile[32][33];
  int c0 = blockIdx.x*32, r0 = blockIdx.y*32;
  int tx = threadIdx.x, ty = threadIdx.y;      // block (32,8)
  #pragma unroll
  for (int ii=0; ii<4; ++ii){
    int r = r0 + ty + ii*8, c = c0 + tx;
    float v = 0.f;
    if (r < R && c < C) v = in[(size_t)r*C + c];
    tile[ty+ii*8][tx] = v;
  }
  __syncthreads();
  #pragma unroll
  for (int ii=0; ii<4; ++ii){
    int orow = c0 + ty + ii*8;   // original col
    int ocol = r0 + tx;          // original row
    if (orow < outR && ocol < R) out[(size_t)orow*R + ocol] = (bf16)tile[tx][ty+ii*8];
  }
}

// ---------------- bf16 MFMA GEMM: C = A(M,K) * B^T(N,K), 128x128 tile, BK=32 ----------------
// EPI 0: plain fp32 store, ldc=N
// EPI 1: GEMM-in split: col<DINNER -> u_pre fp32 (ld DINNER); col>=DINNER -> resb=bf16(silu) (ld DINNER)
// EPI 2: dt: softplus(acc + bias[col]) fp32, ldc=N
template<int EPI>
__global__ __launch_bounds__(256)
void k_gemm_bt(const bf16* __restrict__ A, const bf16* __restrict__ Bt,
               int M, int N, int K,
               float* __restrict__ C0, bf16* __restrict__ C1,
               const float* __restrict__ bias){
  __shared__ bf16 ldsA[128*32];  // 8 KB
  __shared__ bf16 ldsB[128*32];  // 8 KB
  const int tid  = threadIdx.x;
  const int lane = tid & 63;
  const int wave = tid >> 6;
  const int quad = lane >> 4;
  const int mrow = lane & 15;
  const int wr = wave >> 1, wc = wave & 1;     // 2x2 wave grid, each 64x64
  const int bm = blockIdx.y * 128, bn = blockIdx.x * 128;

  floatx4 acc[4][4];
  #pragma unroll
  for (int i=0;i<4;++i)
    #pragma unroll
    for (int j=0;j<4;++j) acc[i][j] = (floatx4){0.f,0.f,0.f,0.f};

  const int ar0 = tid >> 2;           // 0..63: staged row within half-tile
  const int kc  = (tid & 3) * 8;      // k-subchunk (8 bf16 = 16B)
  const bf16* Ag0 = A  + (size_t)(bm + ar0)      * K + kc;
  const bf16* Ag1 = A  + (size_t)(bm + ar0 + 64) * K + kc;
  const bf16* Bg0 = Bt + (size_t)(bn + ar0)      * K + kc;
  const bf16* Bg1 = Bt + (size_t)(bn + ar0 + 64) * K + kc;

  for (int k0 = 0; k0 < K; k0 += 32){
    // async global->LDS staging: lds addr = wave-uniform base + lane*16  (tid*16 bytes)
    gload_lds16(Ag0 + k0, ldsA + (size_t)tid*8);
    gload_lds16(Ag1 + k0, ldsA + (size_t)(tid+256)*8);
    gload_lds16(Bg0 + k0, ldsB + (size_t)tid*8);
    gload_lds16(Bg1 + k0, ldsB + (size_t)(tid+256)*8);
    __syncthreads();

    bf16x8 af[4], bfr[4];
    #pragma unroll
    for (int i=0;i<4;++i)
      af[i] = *(const bf16x8*)(ldsA + (wr*64 + i*16 + mrow)*32 + quad*8);
    #pragma unroll
    for (int j=0;j<4;++j)
      bfr[j] = *(const bf16x8*)(ldsB + (wc*64 + j*16 + mrow)*32 + quad*8);

    #pragma unroll
    for (int i=0;i<4;++i)
      #pragma unroll
      for (int j=0;j<4;++j)
        acc[i][j] = __builtin_amdgcn_mfma_f32_16x16x32_bf16(af[i], bfr[j], acc[i][j], 0,0,0);
    __syncthreads();
  }

  // epilogue: lane holds D[row=quad*4+r][col=mrow] of each 16x16 tile
  #pragma unroll
  for (int i=0;i<4;++i){
    #pragma unroll
    for (int r=0;r<4;++r){
      int row = bm + wr*64 + i*16 + quad*4 + r;
      #pragma unroll
      for (int j=0;j<4;++j){
        int col = bn + wc*64 + j*16 + mrow;
        float v = acc[i][j][r];
        if (EPI == 0){
          C0[(size_t)row*N + col] = v;
        } else if (EPI == 1){
          if (col < DINNER) C0[(size_t)row*DINNER + col] = v;
          else              C1[(size_t)row*DINNER + (col - DINNER)] = (bf16)fsilu(v);
        } else { // EPI == 2
          float z = v + bias[col];
          float sp = (z > 20.f) ? z : log1pf(__expf(z));
          C0[(size_t)row*N + col] = sp;
        }
      }
    }
  }
}

// ---------------- depthwise causal conv (width 4) + bias + SiLU -> bf16 ----------------
__global__ void k_conv_silu(const float* __restrict__ u_pre,
                            const float* __restrict__ conv_w,
                            const float* __restrict__ conv_b,
                            bf16* __restrict__ ub){
  int idx = blockIdx.x*blockDim.x + threadIdx.x;   // MROWS*DINNER
  int d   = idx & (DINNER-1);
  int row = idx >> 11;
  int l   = row & (SEQL-1);
  float4 w = *(const float4*)(conv_w + d*4);
  float wk[4] = {w.x, w.y, w.z, w.w};
  float acc = conv_b[d];
  #pragma unroll
  for (int k=0;k<4;++k){
    int lk = l + k - 3;
    if (lk >= 0) acc += u_pre[(size_t)(row + k - 3)*DINNER + d] * wk[k];
  }
  ub[idx] = (bf16)fsilu(acc);
}

// ---------------- slice x_dbl cols [0,64) -> bf16 ----------------
__global__ void k_cast_dtlow(const float* __restrict__ x_dbl, bf16* __restrict__ out){
  int i = blockIdx.x*blockDim.x + threadIdx.x;   // MROWS*DTRANK
  int r = i >> 6, c = i & 63;
  out[i] = (bf16)x_dbl[(size_t)r*128 + c];
}

// ---------------- scan phase 1: per-chunk transfer (P = prod dA, S = suffix-weighted dBu) ----
// thread t -> d = t&2047, chunk c = (t>>11)&31, batch b = t>>16
__global__ void k_scan_phase1(const float* __restrict__ dt, const bf16* __restrict__ ub,
                              const float* __restrict__ x_dbl, const float* __restrict__ A_log,
                              float* __restrict__ Pbuf, float* __restrict__ Sbuf){
  int t  = blockIdx.x*blockDim.x + threadIdx.x;   // BSZ*NCHUNK*DINNER = 131072
  int d  = t & (DINNER-1);
  int bc = t >> 11;
  int c  = bc & (NCHUNK-1);
  int b  = bc >> 5;
  float an[DSTATE];
  #pragma unroll
  for (int n=0;n<DSTATE;++n) an[n] = -__expf(A_log[d*DSTATE + n]);
  float P[DSTATE], S[DSTATE];
  #pragma unroll
  for (int n=0;n<DSTATE;++n){ P[n]=1.f; S[n]=0.f; }
  int base_row = b*SEQL + c*CLEN;
  for (int s=0;s<CLEN;++s){
    size_t row = base_row + s;
    float dtv = dt[row*DINNER + d];
    float uv  = (float)ub[row*DINNER + d];
    float du  = dtv*uv;
    const floatx4* Bp = (const floatx4*)(x_dbl + row*128 + DTRANK);
    float Bv[DSTATE];
    #pragma unroll
    for (int q=0;q<4;++q){ floatx4 tq = Bp[q]; Bv[q*4]=tq[0]; Bv[q*4+1]=tq[1]; Bv[q*4+2]=tq[2]; Bv[q*4+3]=tq[3]; }
    #pragma unroll
    for (int n=0;n<DSTATE;++n){
      float e = __expf(dtv*an[n]);
      P[n] *= e;
      S[n]  = S[n]*e + du*Bv[n];
    }
  }
  size_t ob = ((size_t)(b*NCHUNK + c)*DSTATE)*DINNER + d;
  #pragma unroll
  for (int n=0;n<DSTATE;++n){ Pbuf[ob + (size_t)n*DINNER] = P[n]; Sbuf[ob + (size_t)n*DINNER] = S[n]; }
}

// ---------------- scan phase 2: sequential chunk combine; Sbuf <- entry state per chunk ------
__global__ void k_scan_phase2(const float* __restrict__ Pbuf, float* __restrict__ Sbuf){
  int t = blockIdx.x*blockDim.x + threadIdx.x;   // BSZ*DINNER = 4096
  int d = t & (DINNER-1);
  int b = t >> 11;
  float h[DSTATE];
  #pragma unroll
  for (int n=0;n<DSTATE;++n) h[n] = 0.f;
  for (int c=0;c<NCHUNK;++c){
    size_t ob = ((size_t)(b*NCHUNK + c)*DSTATE)*DINNER + d;
    #pragma unroll
    for (int n=0;n<DSTATE;++n){
      size_t ix = ob + (size_t)n*DINNER;
      float p = Pbuf[ix], s = Sbuf[ix];
      Sbuf[ix] = h[n];                 // entry state for chunk c
      h[n] = p*h[n] + s;
    }
  }
}

// ---------------- scan phase 3: replay chunk with known entry state; fuse +u*D, *silu(res), bf16 cast
__global__ void k_scan_phase3(const float* __restrict__ dt, const bf16* __restrict__ ub,
                              const float* __restrict__ x_dbl, const float* __restrict__ A_log,
                              const float* __restrict__ Dvec, const float* __restrict__ Hin,
                              const bf16* __restrict__ resb, bf16* __restrict__ yb){
  int t  = blockIdx.x*blockDim.x + threadIdx.x;
  int d  = t & (DINNER-1);
  int bc = t >> 11;
  int c  = bc & (NCHUNK-1);
  int b  = bc >> 5;
  float an[DSTATE];
  #pragma unroll
  for (int n=0;n<DSTATE;++n) an[n] = -__expf(A_log[d*DSTATE + n]);
  float h[DSTATE];
  size_t ob = ((size_t)(b*NCHUNK + c)*DSTATE)*DINNER + d;
  #pragma unroll
  for (int n=0;n<DSTATE;++n) h[n] = Hin[ob + (size_t)n*DINNER];
  float Dd = Dvec[d];
  int base_row = b*SEQL + c*CLEN;
  for (int s=0;s<CLEN;++s){
    size_t row = base_row + s;
    float dtv = dt[row*DINNER + d];
    float uv  = (float)ub[row*DINNER + d];
    float du  = dtv*uv;
    const floatx4* Bp = (const floatx4*)(x_dbl + row*128 + DTRANK);
    const floatx4* Cp = (const floatx4*)(x_dbl + row*128 + DTRANK + DSTATE);
    float Bv[DSTATE], Cv[DSTATE];
    #pragma unroll
    for (int q=0;q<4;++q){
      floatx4 tb = Bp[q]; Bv[q*4]=tb[0]; Bv[q*4+1]=tb[1]; Bv[q*4+2]=tb[2]; Bv[q*4+3]=tb[3];
      floatx4 tc = Cp[q]; Cv[q*4]=tc[0]; Cv[q*4+1]=tc[1]; Cv[q*4+2]=tc[2]; Cv[q*4+3]=tc[3];
    }
    float y = 0.f;
    #pragma unroll
    for (int n=0;n<DSTATE;++n){
      float e = __expf(dtv*an[n]);
      h[n] = h[n]*e + du*Bv[n];
      y += h[n]*Cv[n];
    }
    y = (y + uv*Dd) * (float)resb[row*DINNER + d];
    yb[row*DINNER + d] = (bf16)y;
  }
}

// ---------------- host side ----------------
extern "C" void kernel_launch(void* const* d_in, const int* in_sizes, int n_in,
                              void* d_out, int out_size, void* d_ws, size_t ws_size,
                              hipStream_t stream){
  const float* x      = (const float*)d_in[0];
  const float* W_in   = (const float*)d_in[1];
  const float* conv_w = (const float*)d_in[2];
  const float* conv_b = (const float*)d_in[3];
  const float* W_xproj= (const float*)d_in[4];
  const float* W_dt   = (const float*)d_in[5];
  const float* b_dt   = (const float*)d_in[6];
  const float* A_log  = (const float*)d_in[7];
  const float* Dv     = (const float*)d_in[8];
  const float* W_out  = (const float*)d_in[9];
  float* out = (float*)d_out;

  uint8_t* wp = (uint8_t*)d_ws;
  auto alloc = [&](size_t bytes)->void*{ void* p = wp; wp += (bytes + 255) & ~(size_t)255; return p; };
  bf16*  xb     = (bf16*) alloc((size_t)MROWS*DMODEL*2);
  bf16*  WinT   = (bf16*) alloc((size_t)2*DINNER*DMODEL*2);   // (4096,1024)
  bf16*  WoutT  = (bf16*) alloc((size_t)DMODEL*DINNER*2);     // (1024,2048)
  bf16*  WxT    = (bf16*) alloc((size_t)128*DINNER*2);        // (128,2048) padded
  bf16*  WdtT   = (bf16*) alloc((size_t)DINNER*DTRANK*2);     // (2048,64)
  float* upre_dt= (float*)alloc((size_t)MROWS*DINNER*4);      // u_pre, then reused as dt
  bf16*  resb   = (bf16*) alloc((size_t)MROWS*DINNER*2);      // silu(res)
  bf16*  ub     = (bf16*) alloc((size_t)MROWS*DINNER*2);      // conv+silu output
  float* xdbl   = (float*)alloc((size_t)MROWS*128*4);         // padded ld=128
  bf16*  dtlowb = (bf16*) alloc((size_t)MROWS*DTRANK*2);
  float* Pbuf   = (float*)alloc((size_t)BSZ*NCHUNK*DSTATE*DINNER*4);
  float* Sbuf   = (float*)alloc((size_t)BSZ*NCHUNK*DSTATE*DINNER*4);
  bf16*  yb     = (bf16*) alloc((size_t)MROWS*DINNER*2);

  // prep: casts + transposes
  k_cast_bf16<<<(MROWS*DMODEL/4 + 255)/256, 256, 0, stream>>>(x, xb, MROWS*DMODEL);
  k_transpose_cast<<<dim3(4096/32, 1024/32), dim3(32,8), 0, stream>>>(W_in,    WinT,  1024, 4096, 4096);
  k_transpose_cast<<<dim3(1024/32, 2048/32), dim3(32,8), 0, stream>>>(W_out,   WoutT, 2048, 1024, 1024);
  k_transpose_cast<<<dim3(128/32,  2048/32), dim3(32,8), 0, stream>>>(W_xproj, WxT,   2048,   96,  128);
  k_transpose_cast<<<dim3(2048/32,   64/32), dim3(32,8), 0, stream>>>(W_dt,    WdtT,    64, 2048, 2048);

  // GEMM-in: xr = x @ W_in, split epilogue -> u_pre (fp32) + silu(res) (bf16)
  k_gemm_bt<1><<<dim3(4096/128, 4096/128), 256, 0, stream>>>(xb, WinT, MROWS, 2*DINNER, DMODEL, upre_dt, resb, nullptr);
  // depthwise conv + silu -> ub (bf16)
  k_conv_silu<<<MROWS*DINNER/256, 256, 0, stream>>>(upre_dt, conv_w, conv_b, ub);
  // x_dbl = u @ W_xproj  (N padded to 128)
  k_gemm_bt<0><<<dim3(1, 4096/128), 256, 0, stream>>>(ub, WxT, MROWS, 128, DINNER, xdbl, nullptr, nullptr);
  k_cast_dtlow<<<MROWS*DTRANK/256, 256, 0, stream>>>(xdbl, dtlowb);
  // dt = softplus(dt_low @ W_dt + b_dt)  (overwrites u_pre buffer)
  k_gemm_bt<2><<<dim3(2048/128, 4096/128), 256, 0, stream>>>(dtlowb, WdtT, MROWS, DINNER, DTRANK, upre_dt, nullptr, b_dt);
  // chunked selective scan
  k_scan_phase1<<<BSZ*NCHUNK*DINNER/256, 256, 0, stream>>>(upre_dt, ub, xdbl, A_log, Pbuf, Sbuf);
  k_scan_phase2<<<BSZ*DINNER/256, 256, 0, stream>>>(Pbuf, Sbuf);
  k_scan_phase3<<<BSZ*NCHUNK*DINNER/256, 256, 0, stream>>>(upre_dt, ub, xdbl, A_log, Dv, Sbuf, resb, yb);
  // out = y @ W_out
  k_gemm_bt<0><<<dim3(1024/128, 4096/128), 256, 0, stream>>>(yb, WoutT, MROWS, DMODEL, DINNER, out, nullptr, nullptr);
}

// Round 2
// 399.763 us; speedup vs baseline: 1.5236x; 1.5236x over previous
//
#include <hip/hip_runtime.h>
#include <cstdint>
#include <cstddef>

// ---------------- problem constants ----------------
#define DMODEL 1024
#define DINNER 2048
#define DSTATE 16
#define DCONV  4
#define DTRANK 64
#define BSZ    2
#define SEQL   2048
#define MROWS  (BSZ*SEQL)          // 4096
#define NCHUNK 32                  // scan chunks per sequence
#define CLEN   (SEQL/NCHUNK)       // 64

typedef __bf16 bf16;
typedef bf16  bf16x8 __attribute__((ext_vector_type(8)));
typedef bf16  bf16x4 __attribute__((ext_vector_type(4)));
typedef float floatx4 __attribute__((ext_vector_type(4)));

__device__ __forceinline__ float fsigmoid(float x){ return 1.f/(1.f+__expf(-x)); }
__device__ __forceinline__ float fsilu(float x){ return x*fsigmoid(x); }

__device__ __forceinline__ void gload_lds16(const void* g, void* l){
  __builtin_amdgcn_global_load_lds((__attribute__((address_space(1))) void*)g,
                                   (__attribute__((address_space(3))) void*)l,
                                   16, 0, 0);
}

// ---------------- elementwise cast fp32 -> bf16 (vec4) ----------------
__global__ void k_cast_bf16(const float* __restrict__ in, bf16* __restrict__ out, int n){
  int i = (blockIdx.x*blockDim.x + threadIdx.x)*4;
  if (i < n){
    float4 v = *(const float4*)(in + i);
    bf16x4 o; o[0]=(bf16)v.x; o[1]=(bf16)v.y; o[2]=(bf16)v.z; o[3]=(bf16)v.w;
    *(bf16x4*)(out + i) = o;
  }
}

// ---------------- transpose + cast: out[c][r] = in[r][c], zero-pad rows >= C ----------------
__global__ void k_transpose_cast(const float* __restrict__ in, bf16* __restrict__ out,
                                 int R, int C, int outR){
  __shared__ float tile[32][33];
  int c0 = blockIdx.x*32, r0 = blockIdx.y*32;
  int tx = threadIdx.x, ty = threadIdx.y;      // block (32,8)
  #pragma unroll
  for (int ii=0; ii<4; ++ii){
    int r = r0 + ty + ii*8, c = c0 + tx;
    float v = 0.f;
    if (r < R && c < C) v = in[(size_t)r*C + c];
    tile[ty+ii*8][tx] = v;
  }
  __syncthreads();
  #pragma unroll
  for (int ii=0; ii<4; ++ii){
    int orow = c0 + ty + ii*8;   // original col
    int ocol = r0 + tx;          // original row
    if (orow < outR && ocol < R) out[(size_t)orow*R + ocol] = (bf16)tile[tx][ty+ii*8];
  }
}

// ---------------- bf16 MFMA GEMM: C = A(M,K) * B^T(N,K), 128x128 tile, BK=32 ----------------
// Split-K via gridDim.z: block z handles K slice [z*K/nz, (z+1)*K/nz), stores to C0 + z*M*N.
// EPI 0: plain fp32 store, ldc=N
// EPI 1: GEMM-in split: col<DINNER -> u_pre fp32 (ld DINNER); col>=DINNER -> resb=bf16(silu) (ld DINNER)
// EPI 2: dt: softplus(acc + bias[col]) fp32, ldc=N
template<int EPI>
__global__ __launch_bounds__(256)
void k_gemm_bt(const bf16* __restrict__ A, const bf16* __restrict__ Bt,
               int M, int N, int K,
               float* __restrict__ C0, bf16* __restrict__ C1,
               const float* __restrict__ bias){
  __shared__ bf16 ldsA[128*32];  // 8 KB
  __shared__ bf16 ldsB[128*32];  // 8 KB
  const int tid  = threadIdx.x;
  const int lane = tid & 63;
  const int wave = tid >> 6;
  const int quad = lane >> 4;
  const int mrow = lane & 15;
  const int wr = wave >> 1, wc = wave & 1;     // 2x2 wave grid, each 64x64
  const int bm = blockIdx.y * 128, bn = blockIdx.x * 128;
  const int Ks   = K / gridDim.z;
  const int kbeg = blockIdx.z * Ks;

  floatx4 acc[4][4];
  #pragma unroll
  for (int i=0;i<4;++i)
    #pragma unroll
    for (int j=0;j<4;++j) acc[i][j] = (floatx4){0.f,0.f,0.f,0.f};

  const int ar0 = tid >> 2;           // 0..63: staged row within half-tile
  const int kc  = (tid & 3) * 8;      // k-subchunk (8 bf16 = 16B)
  const bf16* Ag0 = A  + (size_t)(bm + ar0)      * K + kc;
  const bf16* Ag1 = A  + (size_t)(bm + ar0 + 64) * K + kc;
  const bf16* Bg0 = Bt + (size_t)(bn + ar0)      * K + kc;
  const bf16* Bg1 = Bt + (size_t)(bn + ar0 + 64) * K + kc;

  for (int k0 = kbeg; k0 < kbeg + Ks; k0 += 32){
    // async global->LDS staging: lds addr = wave-uniform base + lane*16  (tid*16 bytes)
    gload_lds16(Ag0 + k0, ldsA + (size_t)tid*8);
    gload_lds16(Ag1 + k0, ldsA + (size_t)(tid+256)*8);
    gload_lds16(Bg0 + k0, ldsB + (size_t)tid*8);
    gload_lds16(Bg1 + k0, ldsB + (size_t)(tid+256)*8);
    __syncthreads();

    bf16x8 af[4], bfr[4];
    #pragma unroll
    for (int i=0;i<4;++i)
      af[i] = *(const bf16x8*)(ldsA + (wr*64 + i*16 + mrow)*32 + quad*8);
    #pragma unroll
    for (int j=0;j<4;++j)
      bfr[j] = *(const bf16x8*)(ldsB + (wc*64 + j*16 + mrow)*32 + quad*8);

    #pragma unroll
    for (int i=0;i<4;++i)
      #pragma unroll
      for (int j=0;j<4;++j)
        acc[i][j] = __builtin_amdgcn_mfma_f32_16x16x32_bf16(af[i], bfr[j], acc[i][j], 0,0,0);
    __syncthreads();
  }

  float* Cz = C0 + (size_t)blockIdx.z * M * N;
  // epilogue: lane holds D[row=quad*4+r][col=mrow] of each 16x16 tile
  #pragma unroll
  for (int i=0;i<4;++i){
    #pragma unroll
    for (int r=0;r<4;++r){
      int row = bm + wr*64 + i*16 + quad*4 + r;
      #pragma unroll
      for (int j=0;j<4;++j){
        int col = bn + wc*64 + j*16 + mrow;
        float v = acc[i][j][r];
        if (EPI == 0){
          Cz[(size_t)row*N + col] = v;
        } else if (EPI == 1){
          if (col < DINNER) C0[(size_t)row*DINNER + col] = v;
          else              C1[(size_t)row*DINNER + (col - DINNER)] = (bf16)fsilu(v);
        } else { // EPI == 2
          float z = v + bias[col];
          float sp = (z > 20.f) ? z : log1pf(__expf(z));
          C0[(size_t)row*N + col] = sp;
        }
      }
    }
  }
}

// ---------------- split-K reduce for x_dbl (+ fused dt_low bf16 slice cast) ----------------
__global__ void k_xdbl_reduce(const float* __restrict__ part, float* __restrict__ xdbl,
                              bf16* __restrict__ dtlowb){
  int t = blockIdx.x*blockDim.x + threadIdx.x;   // MROWS*128/4 threads
  int i4 = t*4;
  floatx4 acc = (floatx4){0.f,0.f,0.f,0.f};
  #pragma unroll
  for (int z=0; z<8; ++z)
    acc += *(const floatx4*)(part + (size_t)z*MROWS*128 + i4);
  *(floatx4*)(xdbl + i4) = acc;
  int r = i4 >> 7, c = i4 & 127;
  if (c < DTRANK){
    bf16x4 o; o[0]=(bf16)acc[0]; o[1]=(bf16)acc[1]; o[2]=(bf16)acc[2]; o[3]=(bf16)acc[3];
    *(bf16x4*)(dtlowb + (size_t)r*DTRANK + c) = o;
  }
}

// ---------------- depthwise causal conv (width 4) + bias + SiLU -> bf16 ----------------
__global__ void k_conv_silu(const float* __restrict__ u_pre,
                            const float* __restrict__ conv_w,
                            const float* __restrict__ conv_b,
                            bf16* __restrict__ ub){
  int idx = blockIdx.x*blockDim.x + threadIdx.x;   // MROWS*DINNER
  int d   = idx & (DINNER-1);
  int row = idx >> 11;
  int l   = row & (SEQL-1);
  float4 w = *(const float4*)(conv_w + d*4);
  float wk[4] = {w.x, w.y, w.z, w.w};
  float acc = conv_b[d];
  #pragma unroll
  for (int k=0;k<4;++k){
    int lk = l + k - 3;
    if (lk >= 0) acc += u_pre[(size_t)(row + k - 3)*DINNER + d] * wk[k];
  }
  ub[idx] = (bf16)fsilu(acc);
}

// ---------------- scan phase 1: 4 states/thread, per-chunk transfer (P, S) ----------------
// t = ((b*NCHUNK + c)*DINNER + d)*4 + g ; states n = g*4 .. g*4+3
// P/S layout: [(b,c,d), n] contiguous in n (16 floats)
__global__ void k_scan_phase1(const float* __restrict__ dt, const bf16* __restrict__ ub,
                              const float* __restrict__ x_dbl, const float* __restrict__ A_log,
                              float* __restrict__ Pbuf, float* __restrict__ Sbuf){
  int t  = blockIdx.x*blockDim.x + threadIdx.x;   // BSZ*NCHUNK*DINNER*4 = 524288
  int g  = t & 3;
  int d  = (t >> 2) & (DINNER-1);
  int bc = t >> 13;
  int c  = bc & (NCHUNK-1);
  int b  = bc >> 5;
  floatx4 alog = *(const floatx4*)(A_log + d*DSTATE + g*4);
  float an[4];
  #pragma unroll
  for (int n=0;n<4;++n) an[n] = -__expf(alog[n]);
  float P[4] = {1.f,1.f,1.f,1.f}, S[4] = {0.f,0.f,0.f,0.f};
  int base_row = b*SEQL + c*CLEN;
  for (int s=0;s<CLEN;++s){
    size_t row = base_row + s;
    float dtv = dt[row*DINNER + d];
    float uv  = (float)ub[row*DINNER + d];
    float du  = dtv*uv;
    floatx4 Bv = *(const floatx4*)(x_dbl + row*128 + DTRANK + g*4);
    #pragma unroll
    for (int n=0;n<4;++n){
      float e = __expf(dtv*an[n]);
      P[n] *= e;
      S[n]  = fmaf(S[n], e, du*Bv[n]);
    }
  }
  size_t ob = ((size_t)bc*DINNER + d)*DSTATE + g*4;
  floatx4 Pv = {P[0],P[1],P[2],P[3]}, Sv = {S[0],S[1],S[2],S[3]};
  *(floatx4*)(Pbuf + ob) = Pv;
  *(floatx4*)(Sbuf + ob) = Sv;
}

// ---------------- scan phase 2: chunk combine over (b,d,n); Sbuf <- entry state ----------
__global__ void k_scan_phase2(const float* __restrict__ Pbuf, float* __restrict__ Sbuf){
  int t = blockIdx.x*blockDim.x + threadIdx.x;   // BSZ*DINNER*DSTATE = 65536
  int b   = t >> 15;
  int rem = t & 32767;           // d*16 + n
  float h = 0.f;
  for (int c=0;c<NCHUNK;++c){
    size_t ix = (size_t)(b*NCHUNK + c)*DINNER*DSTATE + rem;
    float p = Pbuf[ix], s = Sbuf[ix];
    Sbuf[ix] = h;                // entry state for chunk c
    h = fmaf(p, h, s);
  }
}

// ---------------- scan phase 3: replay with known entry state; fuse +u*D, *silu(res) -----
__global__ void k_scan_phase3(const float* __restrict__ dt, const bf16* __restrict__ ub,
                              const float* __restrict__ x_dbl, const float* __restrict__ A_log,
                              const float* __restrict__ Dvec, const float* __restrict__ Hin,
                              const bf16* __restrict__ resb, bf16* __restrict__ yb){
  int t  = blockIdx.x*blockDim.x + threadIdx.x;
  int g  = t & 3;
  int d  = (t >> 2) & (DINNER-1);
  int bc = t >> 13;
  int c  = bc & (NCHUNK-1);
  int b  = bc >> 5;
  floatx4 alog = *(const floatx4*)(A_log + d*DSTATE + g*4);
  float an[4];
  #pragma unroll
  for (int n=0;n<4;++n) an[n] = -__expf(alog[n]);
  floatx4 h = *(const floatx4*)(Hin + ((size_t)bc*DINNER + d)*DSTATE + g*4);
  float Dd = Dvec[d];
  int base_row = b*SEQL + c*CLEN;
  for (int s=0;s<CLEN;++s){
    size_t row = base_row + s;
    float dtv = dt[row*DINNER + d];
    float uv  = (float)ub[row*DINNER + d];
    float du  = dtv*uv;
    floatx4 Bv = *(const floatx4*)(x_dbl + row*128 + DTRANK + g*4);
    floatx4 Cv = *(const floatx4*)(x_dbl + row*128 + DTRANK + DSTATE + g*4);
    float y = 0.f;
    #pragma unroll
    for (int n=0;n<4;++n){
      float e = __expf(dtv*an[n]);
      h[n] = fmaf(h[n], e, du*Bv[n]);
      y = fmaf(h[n], Cv[n], y);
    }
    y += __shfl_xor(y, 1);
    y += __shfl_xor(y, 2);
    if (g == 0){
      y = (y + uv*Dd) * (float)resb[row*DINNER + d];
      yb[row*DINNER + d] = (bf16)y;
    }
  }
}

// ---------------- host side ----------------
extern "C" void kernel_launch(void* const* d_in, const int* in_sizes, int n_in,
                              void* d_out, int out_size, void* d_ws, size_t ws_size,
                              hipStream_t stream){
  const float* x      = (const float*)d_in[0];
  const float* W_in   = (const float*)d_in[1];
  const float* conv_w = (const float*)d_in[2];
  const float* conv_b = (const float*)d_in[3];
  const float* W_xproj= (const float*)d_in[4];
  const float* W_dt   = (const float*)d_in[5];
  const float* b_dt   = (const float*)d_in[6];
  const float* A_log  = (const float*)d_in[7];
  const float* Dv     = (const float*)d_in[8];
  const float* W_out  = (const float*)d_in[9];
  float* out = (float*)d_out;

  uint8_t* wp = (uint8_t*)d_ws;
  auto alloc = [&](size_t bytes)->void*{ void* p = wp; wp += (bytes + 255) & ~(size_t)255; return p; };
  bf16*  xb     = (bf16*) alloc((size_t)MROWS*DMODEL*2);
  bf16*  WinT   = (bf16*) alloc((size_t)2*DINNER*DMODEL*2);   // (4096,1024)
  bf16*  WoutT  = (bf16*) alloc((size_t)DMODEL*DINNER*2);     // (1024,2048)
  bf16*  WxT    = (bf16*) alloc((size_t)128*DINNER*2);        // (128,2048) padded
  bf16*  WdtT   = (bf16*) alloc((size_t)DINNER*DTRANK*2);     // (2048,64)
  float* upre_dt= (float*)alloc((size_t)MROWS*DINNER*4);      // u_pre, then reused as dt
  bf16*  resb   = (bf16*) alloc((size_t)MROWS*DINNER*2);      // silu(res)
  bf16*  ub     = (bf16*) alloc((size_t)MROWS*DINNER*2);      // conv+silu output
  float* xdbl   = (float*)alloc((size_t)MROWS*128*4);         // padded ld=128
  bf16*  dtlowb = (bf16*) alloc((size_t)MROWS*DTRANK*2);
  // 16 MB region shared by: split-K partials (early), then Pbuf+Sbuf (scan phases)
  float* scanPS = (float*)alloc((size_t)2*BSZ*NCHUNK*DSTATE*DINNER*4);
  float* Pbuf   = scanPS;
  float* Sbuf   = scanPS + (size_t)BSZ*NCHUNK*DSTATE*DINNER;
  float* xdbl_part = scanPS;                                  // 8 z-slices * 2 MB = 16 MB
  bf16*  yb     = (bf16*) alloc((size_t)MROWS*DINNER*2);

  // prep: casts + transposes
  k_cast_bf16<<<(MROWS*DMODEL/4 + 255)/256, 256, 0, stream>>>(x, xb, MROWS*DMODEL);
  k_transpose_cast<<<dim3(4096/32, 1024/32), dim3(32,8), 0, stream>>>(W_in,    WinT,  1024, 4096, 4096);
  k_transpose_cast<<<dim3(1024/32, 2048/32), dim3(32,8), 0, stream>>>(W_out,   WoutT, 2048, 1024, 1024);
  k_transpose_cast<<<dim3(128/32,  2048/32), dim3(32,8), 0, stream>>>(W_xproj, WxT,   2048,   96,  128);
  k_transpose_cast<<<dim3(2048/32,   64/32), dim3(32,8), 0, stream>>>(W_dt,    WdtT,    64, 2048, 2048);

  // GEMM-in: xr = x @ W_in, split epilogue -> u_pre (fp32) + silu(res) (bf16)
  k_gemm_bt<1><<<dim3(4096/128, 4096/128), 256, 0, stream>>>(xb, WinT, MROWS, 2*DINNER, DMODEL, upre_dt, resb, nullptr);
  // depthwise conv + silu -> ub (bf16)
  k_conv_silu<<<MROWS*DINNER/256, 256, 0, stream>>>(upre_dt, conv_w, conv_b, ub);
  // x_dbl = u @ W_xproj  (N padded to 128), split-K=8 -> partials -> reduce (+dt_low cast)
  k_gemm_bt<0><<<dim3(1, 4096/128, 8), 256, 0, stream>>>(ub, WxT, MROWS, 128, DINNER, xdbl_part, nullptr, nullptr);
  k_xdbl_reduce<<<(MROWS*128/4)/256, 256, 0, stream>>>(xdbl_part, xdbl, dtlowb);
  // dt = softplus(dt_low @ W_dt + b_dt)  (overwrites u_pre buffer)
  k_gemm_bt<2><<<dim3(2048/128, 4096/128), 256, 0, stream>>>(dtlowb, WdtT, MROWS, DINNER, DTRANK, upre_dt, nullptr, b_dt);
  // chunked selective scan (4 states/thread, 100% occupancy)
  k_scan_phase1<<<BSZ*NCHUNK*DINNER*4/256, 256, 0, stream>>>(upre_dt, ub, xdbl, A_log, Pbuf, Sbuf);
  k_scan_phase2<<<BSZ*DINNER*DSTATE/256, 256, 0, stream>>>(Pbuf, Sbuf);
  k_scan_phase3<<<BSZ*NCHUNK*DINNER*4/256, 256, 0, stream>>>(upre_dt, ub, xdbl, A_log, Dv, Sbuf, resb, yb);
  // out = y @ W_out
  k_gemm_bt<0><<<dim3(1024/128, 4096/128), 256, 0, stream>>>(yb, WoutT, MROWS, DMODEL, DINNER, out, nullptr, nullptr);
}

// Round 3
// 380.750 us; speedup vs baseline: 1.5997x; 1.0499x over previous
//
#include <hip/hip_runtime.h>
#include <cstdint>
#include <cstddef>

// ---------------- problem constants ----------------
#define DMODEL 1024
#define DINNER 2048
#define DSTATE 16
#define DCONV  4
#define DTRANK 64
#define BSZ    2
#define SEQL   2048
#define MROWS  (BSZ*SEQL)          // 4096
#define NCHUNK 32                  // scan chunks per sequence
#define CLEN   (SEQL/NCHUNK)       // 64

typedef __bf16 bf16;
typedef bf16  bf16x8 __attribute__((ext_vector_type(8)));
typedef bf16  bf16x4 __attribute__((ext_vector_type(4)));
typedef float floatx4 __attribute__((ext_vector_type(4)));

__device__ __forceinline__ float fsigmoid(float x){ return 1.f/(1.f+__expf(-x)); }
__device__ __forceinline__ float fsilu(float x){ return x*fsigmoid(x); }

__device__ __forceinline__ void gload_lds16(const void* g, void* l){
  __builtin_amdgcn_global_load_lds((__attribute__((address_space(1))) void*)g,
                                   (__attribute__((address_space(3))) void*)l,
                                   16, 0, 0);
}

// ---------------- elementwise cast fp32 -> bf16 (vec4) ----------------
__global__ void k_cast_bf16(const float* __restrict__ in, bf16* __restrict__ out, int n){
  int i = (blockIdx.x*blockDim.x + threadIdx.x)*4;
  if (i < n){
    float4 v = *(const float4*)(in + i);
    bf16x4 o; o[0]=(bf16)v.x; o[1]=(bf16)v.y; o[2]=(bf16)v.z; o[3]=(bf16)v.w;
    *(bf16x4*)(out + i) = o;
  }
}

// ---------------- transpose + cast: out[c][r] = in[r][c], zero-pad rows >= C ----------------
__global__ void k_transpose_cast(const float* __restrict__ in, bf16* __restrict__ out,
                                 int R, int C, int outR){
  __shared__ float tile[32][33];
  int c0 = blockIdx.x*32, r0 = blockIdx.y*32;
  int tx = threadIdx.x, ty = threadIdx.y;      // block (32,8)
  #pragma unroll
  for (int ii=0; ii<4; ++ii){
    int r = r0 + ty + ii*8, c = c0 + tx;
    float v = 0.f;
    if (r < R && c < C) v = in[(size_t)r*C + c];
    tile[ty+ii*8][tx] = v;
  }
  __syncthreads();
  #pragma unroll
  for (int ii=0; ii<4; ++ii){
    int orow = c0 + ty + ii*8;   // original col
    int ocol = r0 + tx;          // original row
    if (orow < outR && ocol < R) out[(size_t)orow*R + ocol] = (bf16)tile[tx][ty+ii*8];
  }
}

// ---------------- bf16 MFMA GEMM: C = A(M,K) * B^T(N,K), 128x128 tile, BK=32 ----------------
// LDS k-chunk XOR swizzle: slot s of row r holds global chunk s ^ ((r>>1)&3).
//   Staging lane writes tid*16B (contiguous, global_load_lds constraint); fragment
//   ds_read_b128 start banks become 2-way within each quarter-wave (free) vs 8-way before.
// Split-K via gridDim.z: block z handles K slice, EPI0 stores to C0 + z*M*N.
// EPI 0: plain fp32 store, ldc=N (partials)
// EPI 1: GEMM-in split: col<DINNER -> u_pre bf16 (C1); col>=DINNER -> resb=bf16(silu) (C2)
// EPI 2: dt: bf16(softplus(acc + bias[col])) -> C1, ldc=N
template<int EPI>
__global__ __launch_bounds__(256)
void k_gemm_bt(const bf16* __restrict__ A, const bf16* __restrict__ Bt,
               int M, int N, int K,
               float* __restrict__ C0, bf16* __restrict__ C1, bf16* __restrict__ C2,
               const float* __restrict__ bias){
  __shared__ bf16 ldsA[128*32];  // 8 KB
  __shared__ bf16 ldsB[128*32];  // 8 KB
  const int tid  = threadIdx.x;
  const int lane = tid & 63;
  const int wave = tid >> 6;
  const int quad = lane >> 4;
  const int mrow = lane & 15;
  const int wr = wave >> 1, wc = wave & 1;     // 2x2 wave grid, each 64x64
  const int bm = blockIdx.y * 128, bn = blockIdx.x * 128;
  const int Ks   = K / gridDim.z;
  const int kbeg = blockIdx.z * Ks;

  floatx4 acc[4][4];
  #pragma unroll
  for (int i=0;i<4;++i)
    #pragma unroll
    for (int j=0;j<4;++j) acc[i][j] = (floatx4){0.f,0.f,0.f,0.f};

  const int ar0 = tid >> 2;                    // 0..63: staged row within half-tile
  const int kc  = ((tid & 3) ^ ((ar0 >> 1) & 3)) * 8;   // swizzled k-subchunk (8 bf16 = 16B)
  const bf16* Ag0 = A  + (size_t)(bm + ar0)      * K + kc;
  const bf16* Ag1 = A  + (size_t)(bm + ar0 + 64) * K + kc;
  const bf16* Bg0 = Bt + (size_t)(bn + ar0)      * K + kc;
  const bf16* Bg1 = Bt + (size_t)(bn + ar0 + 64) * K + kc;

  const int ksl = (mrow >> 1) & 3;             // read-side swizzle key

  for (int k0 = kbeg; k0 < kbeg + Ks; k0 += 32){
    // async global->LDS staging: lds addr = wave-uniform base + lane*16  (tid*16 bytes)
    gload_lds16(Ag0 + k0, ldsA + (size_t)tid*8);
    gload_lds16(Ag1 + k0, ldsA + (size_t)(tid+256)*8);
    gload_lds16(Bg0 + k0, ldsB + (size_t)tid*8);
    gload_lds16(Bg1 + k0, ldsB + (size_t)(tid+256)*8);
    __syncthreads();

    bf16x8 af[4], bfr[4];
    #pragma unroll
    for (int i=0;i<4;++i)
      af[i] = *(const bf16x8*)(ldsA + (wr*64 + i*16 + mrow)*32 + (quad ^ ksl)*8);
    #pragma unroll
    for (int j=0;j<4;++j)
      bfr[j] = *(const bf16x8*)(ldsB + (wc*64 + j*16 + mrow)*32 + (quad ^ ksl)*8);

    #pragma unroll
    for (int i=0;i<4;++i)
      #pragma unroll
      for (int j=0;j<4;++j)
        acc[i][j] = __builtin_amdgcn_mfma_f32_16x16x32_bf16(af[i], bfr[j], acc[i][j], 0,0,0);
    __syncthreads();
  }

  float* Cz = C0 + (size_t)blockIdx.z * M * N;
  // epilogue: lane holds D[row=quad*4+r][col=mrow] of each 16x16 tile
  #pragma unroll
  for (int i=0;i<4;++i){
    #pragma unroll
    for (int r=0;r<4;++r){
      int row = bm + wr*64 + i*16 + quad*4 + r;
      #pragma unroll
      for (int j=0;j<4;++j){
        int col = bn + wc*64 + j*16 + mrow;
        float v = acc[i][j][r];
        if (EPI == 0){
          Cz[(size_t)row*N + col] = v;
        } else if (EPI == 1){
          if (col < DINNER) C1[(size_t)row*DINNER + col] = (bf16)v;
          else              C2[(size_t)row*DINNER + (col - DINNER)] = (bf16)fsilu(v);
        } else { // EPI == 2
          float z = v + bias[col];
          float sp = (z > 20.f) ? z : log1pf(__expf(z));
          C1[(size_t)row*N + col] = (bf16)sp;
        }
      }
    }
  }
}

// ---------------- split-K reduce for x_dbl (+ fused dt_low bf16 slice cast) ----------------
__global__ void k_xdbl_reduce(const float* __restrict__ part, float* __restrict__ xdbl,
                              bf16* __restrict__ dtlowb){
  int t = blockIdx.x*blockDim.x + threadIdx.x;   // MROWS*128/4 threads
  int i4 = t*4;
  floatx4 acc = (floatx4){0.f,0.f,0.f,0.f};
  #pragma unroll
  for (int z=0; z<8; ++z)
    acc += *(const floatx4*)(part + (size_t)z*MROWS*128 + i4);
  *(floatx4*)(xdbl + i4) = acc;
  int r = i4 >> 7, c = i4 & 127;
  if (c < DTRANK){
    bf16x4 o; o[0]=(bf16)acc[0]; o[1]=(bf16)acc[1]; o[2]=(bf16)acc[2]; o[3]=(bf16)acc[3];
    *(bf16x4*)(dtlowb + (size_t)r*DTRANK + c) = o;
  }
}

// ---------------- split-K=2 reduce for out GEMM (fp32) ----------------
__global__ void k_out_reduce(const float* __restrict__ part, float* __restrict__ out){
  int i4 = (blockIdx.x*blockDim.x + threadIdx.x)*4;
  floatx4 a = *(const floatx4*)(part + i4);
  floatx4 b = *(const floatx4*)(part + (size_t)MROWS*DMODEL + i4);
  *(floatx4*)(out + i4) = a + b;
}

// ---------------- depthwise causal conv (width 4) + bias + SiLU -> bf16 ----------------
__global__ void k_conv_silu(const bf16* __restrict__ u_pre,
                            const float* __restrict__ conv_w,
                            const float* __restrict__ conv_b,
                            bf16* __restrict__ ub){
  int idx = blockIdx.x*blockDim.x + threadIdx.x;   // MROWS*DINNER
  int d   = idx & (DINNER-1);
  int row = idx >> 11;
  int l   = row & (SEQL-1);
  float4 w = *(const float4*)(conv_w + d*4);
  float wk[4] = {w.x, w.y, w.z, w.w};
  float acc = conv_b[d];
  #pragma unroll
  for (int k=0;k<4;++k){
    int lk = l + k - 3;
    if (lk >= 0) acc += (float)u_pre[(size_t)(row + k - 3)*DINNER + d] * wk[k];
  }
  ub[idx] = (bf16)fsilu(acc);
}

// ---------------- scan phase 1: 4 states/thread, per-chunk transfer (P, S) ----------------
// t = ((b*NCHUNK + c)*DINNER + d)*4 + g ; states n = g*4 .. g*4+3
// P/S layout: [(b,c,d), n] contiguous in n (16 floats)
__global__ void k_scan_phase1(const bf16* __restrict__ dt, const bf16* __restrict__ ub,
                              const float* __restrict__ x_dbl, const float* __restrict__ A_log,
                              float* __restrict__ Pbuf, float* __restrict__ Sbuf){
  int t  = blockIdx.x*blockDim.x + threadIdx.x;   // BSZ*NCHUNK*DINNER*4 = 524288
  int g  = t & 3;
  int d  = (t >> 2) & (DINNER-1);
  int bc = t >> 13;
  int c  = bc & (NCHUNK-1);
  int b  = bc >> 5;
  floatx4 alog = *(const floatx4*)(A_log + d*DSTATE + g*4);
  float an[4];
  #pragma unroll
  for (int n=0;n<4;++n) an[n] = -__expf(alog[n]);
  float P[4] = {1.f,1.f,1.f,1.f}, S[4] = {0.f,0.f,0.f,0.f};
  int base_row = b*SEQL + c*CLEN;
  for (int s=0;s<CLEN;++s){
    size_t row = base_row + s;
    float dtv = (float)dt[row*DINNER + d];
    float uv  = (float)ub[row*DINNER + d];
    float du  = dtv*uv;
    floatx4 Bv = *(const floatx4*)(x_dbl + row*128 + DTRANK + g*4);
    #pragma unroll
    for (int n=0;n<4;++n){
      float e = __expf(dtv*an[n]);
      P[n] *= e;
      S[n]  = fmaf(S[n], e, du*Bv[n]);
    }
  }
  size_t ob = ((size_t)bc*DINNER + d)*DSTATE + g*4;
  floatx4 Pv = {P[0],P[1],P[2],P[3]}, Sv = {S[0],S[1],S[2],S[3]};
  *(floatx4*)(Pbuf + ob) = Pv;
  *(floatx4*)(Sbuf + ob) = Sv;
}

// ---------------- scan phase 2: chunk combine over (b,d,n); Sbuf <- entry state ----------
__global__ void k_scan_phase2(const float* __restrict__ Pbuf, float* __restrict__ Sbuf){
  int t = blockIdx.x*blockDim.x + threadIdx.x;   // BSZ*DINNER*DSTATE = 65536
  int b   = t >> 15;
  int rem = t & 32767;           // d*16 + n
  float h = 0.f;
  for (int c=0;c<NCHUNK;++c){
    size_t ix = (size_t)(b*NCHUNK + c)*DINNER*DSTATE + rem;
    float p = Pbuf[ix], s = Sbuf[ix];
    Sbuf[ix] = h;                // entry state for chunk c
    h = fmaf(p, h, s);
  }
}

// ---------------- scan phase 3: replay with known entry state; fuse +u*D, *silu(res) -----
__global__ void k_scan_phase3(const bf16* __restrict__ dt, const bf16* __restrict__ ub,
                              const float* __restrict__ x_dbl, const float* __restrict__ A_log,
                              const float* __restrict__ Dvec, const float* __restrict__ Hin,
                              const bf16* __restrict__ resb, bf16* __restrict__ yb){
  int t  = blockIdx.x*blockDim.x + threadIdx.x;
  int g  = t & 3;
  int d  = (t >> 2) & (DINNER-1);
  int bc = t >> 13;
  int c  = bc & (NCHUNK-1);
  int b  = bc >> 5;
  floatx4 alog = *(const floatx4*)(A_log + d*DSTATE + g*4);
  float an[4];
  #pragma unroll
  for (int n=0;n<4;++n) an[n] = -__expf(alog[n]);
  floatx4 h = *(const floatx4*)(Hin + ((size_t)bc*DINNER + d)*DSTATE + g*4);
  float Dd = Dvec[d];
  int base_row = b*SEQL + c*CLEN;
  for (int s=0;s<CLEN;++s){
    size_t row = base_row + s;
    float dtv = (float)dt[row*DINNER + d];
    float uv  = (float)ub[row*DINNER + d];
    float du  = dtv*uv;
    floatx4 Bv = *(const floatx4*)(x_dbl + row*128 + DTRANK + g*4);
    floatx4 Cv = *(const floatx4*)(x_dbl + row*128 + DTRANK + DSTATE + g*4);
    float y = 0.f;
    #pragma unroll
    for (int n=0;n<4;++n){
      float e = __expf(dtv*an[n]);
      h[n] = fmaf(h[n], e, du*Bv[n]);
      y = fmaf(h[n], Cv[n], y);
    }
    y += __shfl_xor(y, 1);
    y += __shfl_xor(y, 2);
    if (g == 0){
      y = (y + uv*Dd) * (float)resb[row*DINNER + d];
      yb[row*DINNER + d] = (bf16)y;
    }
  }
}

// ---------------- host side ----------------
extern "C" void kernel_launch(void* const* d_in, const int* in_sizes, int n_in,
                              void* d_out, int out_size, void* d_ws, size_t ws_size,
                              hipStream_t stream){
  const float* x      = (const float*)d_in[0];
  const float* W_in   = (const float*)d_in[1];
  const float* conv_w = (const float*)d_in[2];
  const float* conv_b = (const float*)d_in[3];
  const float* W_xproj= (const float*)d_in[4];
  const float* W_dt   = (const float*)d_in[5];
  const float* b_dt   = (const float*)d_in[6];
  const float* A_log  = (const float*)d_in[7];
  const float* Dv     = (const float*)d_in[8];
  const float* W_out  = (const float*)d_in[9];
  float* out = (float*)d_out;

  uint8_t* wp = (uint8_t*)d_ws;
  auto alloc = [&](size_t bytes)->void*{ void* p = wp; wp += (bytes + 255) & ~(size_t)255; return p; };
  bf16*  xb     = (bf16*) alloc((size_t)MROWS*DMODEL*2);
  bf16*  WinT   = (bf16*) alloc((size_t)2*DINNER*DMODEL*2);   // (4096,1024)
  bf16*  WoutT  = (bf16*) alloc((size_t)DMODEL*DINNER*2);     // (1024,2048)
  bf16*  WxT    = (bf16*) alloc((size_t)128*DINNER*2);        // (128,2048) padded
  bf16*  WdtT   = (bf16*) alloc((size_t)DINNER*DTRANK*2);     // (2048,64)
  // updt (16MB: u_pre bf16, then dt bf16) immediately followed by scanPS (16MB):
  // their 32MB span is reused as GEMM-out split-K partials after scan phase3.
  bf16*  updt   = (bf16*) alloc((size_t)MROWS*DINNER*2);
  float* scanPS = (float*)alloc((size_t)2*BSZ*NCHUNK*DSTATE*DINNER*4);  // 16MB
  float* Pbuf   = scanPS;
  float* Sbuf   = scanPS + (size_t)BSZ*NCHUNK*DSTATE*DINNER;
  float* xdbl_part = scanPS;                                  // 8 z-slices * 2 MB
  float* outpart   = (float*)updt;                            // 2 z-slices * 16 MB
  bf16*  resb   = (bf16*) alloc((size_t)MROWS*DINNER*2);      // silu(res)
  bf16*  ub     = (bf16*) alloc((size_t)MROWS*DINNER*2);      // conv+silu output
  float* xdbl   = (float*)alloc((size_t)MROWS*128*4);         // padded ld=128
  bf16*  dtlowb = (bf16*) alloc((size_t)MROWS*DTRANK*2);
  bf16*  yb     = (bf16*) alloc((size_t)MROWS*DINNER*2);

  // prep: casts + transposes
  k_cast_bf16<<<(MROWS*DMODEL/4 + 255)/256, 256, 0, stream>>>(x, xb, MROWS*DMODEL);
  k_transpose_cast<<<dim3(4096/32, 1024/32), dim3(32,8), 0, stream>>>(W_in,    WinT,  1024, 4096, 4096);
  k_transpose_cast<<<dim3(1024/32, 2048/32), dim3(32,8), 0, stream>>>(W_out,   WoutT, 2048, 1024, 1024);
  k_transpose_cast<<<dim3(128/32,  2048/32), dim3(32,8), 0, stream>>>(W_xproj, WxT,   2048,   96,  128);
  k_transpose_cast<<<dim3(2048/32,   64/32), dim3(32,8), 0, stream>>>(W_dt,    WdtT,    64, 2048, 2048);

  // GEMM-in: xr = x @ W_in, split epilogue -> u_pre (bf16) + silu(res) (bf16)
  k_gemm_bt<1><<<dim3(4096/128, 4096/128), 256, 0, stream>>>(xb, WinT, MROWS, 2*DINNER, DMODEL, nullptr, updt, resb, nullptr);
  // depthwise conv + silu -> ub (bf16)
  k_conv_silu<<<MROWS*DINNER/256, 256, 0, stream>>>(updt, conv_w, conv_b, ub);
  // x_dbl = u @ W_xproj  (N padded to 128), split-K=8 -> partials -> reduce (+dt_low cast)
  k_gemm_bt<0><<<dim3(1, 4096/128, 8), 256, 0, stream>>>(ub, WxT, MROWS, 128, DINNER, xdbl_part, nullptr, nullptr, nullptr);
  k_xdbl_reduce<<<(MROWS*128/4)/256, 256, 0, stream>>>(xdbl_part, xdbl, dtlowb);
  // dt = softplus(dt_low @ W_dt + b_dt) -> bf16 (overwrites u_pre buffer)
  k_gemm_bt<2><<<dim3(2048/128, 4096/128), 256, 0, stream>>>(dtlowb, WdtT, MROWS, DINNER, DTRANK, nullptr, updt, nullptr, b_dt);
  // chunked selective scan (4 states/thread)
  k_scan_phase1<<<BSZ*NCHUNK*DINNER*4/256, 256, 0, stream>>>(updt, ub, xdbl, A_log, Pbuf, Sbuf);
  k_scan_phase2<<<BSZ*DINNER*DSTATE/256, 256, 0, stream>>>(Pbuf, Sbuf);
  k_scan_phase3<<<BSZ*NCHUNK*DINNER*4/256, 256, 0, stream>>>(updt, ub, xdbl, A_log, Dv, Sbuf, resb, yb);
  // out = y @ W_out, split-K=2 (partials overwrite dead updt+scanPS region) -> reduce
  k_gemm_bt<0><<<dim3(1024/128, 4096/128, 2), 256, 0, stream>>>(yb, WoutT, MROWS, DMODEL, DINNER, outpart, nullptr, nullptr, nullptr);
  k_out_reduce<<<(MROWS*DMODEL/4)/256, 256, 0, stream>>>(outpart, out);
}